// Round 11
// baseline (183.624 us; speedup 1.0000x reference)
//
#include <hip/hip_runtime.h>
#include <hip/hip_bf16.h>
#include <hip/hip_cooperative_groups.h>

#define GG    96     // grid size
#define DD    128    // feature dim
#define KC    32     // K-chunk = MFMA K
#define APAD  40     // padded LDS row stride in ushorts (80 B)
#define RCUT  18     // gaussian support radius in rows (exp(-18^2/32)=4e-5, validated R10)
#define NPER  512    // nodes per batch (N/B)
#define NPB   16     // nodes per preprocess block

typedef __attribute__((ext_vector_type(8))) short short8v;  // 8 bf16 = 4 VGPRs
typedef __attribute__((ext_vector_type(4))) float f32x4;    // MFMA acc

// ================= preprocess body (R8-validated) =================
__device__ void preprocess_body(
    const float* __restrict__ pos, const float* __restrict__ log_sigma,
    const float* __restrict__ f,
    int* __restrict__ pref,
    float* __restrict__ wygT, float* __restrict__ wxT,
    unsigned short* __restrict__ fTh, unsigned short* __restrict__ fTl,
    int Nn)
{
    const int blk   = (int)blockIdx.x;
    const int bpb   = NPER / NPB;             // 32 blocks per batch
    const int b     = blk / bpb;
    const int j0loc = (blk % bpb) * NPB;
    const int nbase = b * NPER;
    const int t     = (int)threadIdx.x;
    const int w     = t >> 6, lane = t & 63;

    __shared__ int ghist[8][GG];
    __shared__ int gpart[8][GG];
    __shared__ int spre[GG + 1];
    __shared__ int inv[NPER];
    __shared__ int sn[NPB];
    __shared__ int wtot;
    __shared__ float spy[NPB], spx[NPB], sG[NPB];
    __shared__ float sPy[16][NPB], sPx[16][NPB];
    __shared__ __align__(16) float ubig[GG * NPB * 2];   // 12 KiB, phased reuse
    float (*sE)[NPB] = (float(*)[NPB])ubig;              // weights phase
    float (*sX)[NPB] = (float(*)[NPB])(ubig + GG * NPB);
    float (*sT)[17]  = (float(*)[17])ubig;               // transpose phase

    // ---- (a) in-LDS counting sort of the whole batch (redundant per block) ----
    for (int i = t; i < 8 * GG; i += 256) (&ghist[0][0])[i] = 0;
    __syncthreads();

    int binA, binB;
    {
        float pyA = pos[(size_t)(nbase + t) * 2];
        float pyB = pos[(size_t)(nbase + t + 256) * 2];
        binA = (int)floorf(pyA); binA = binA < 0 ? 0 : (binA > GG - 1 ? GG - 1 : binA);
        binB = (int)floorf(pyB); binB = binB < 0 ? 0 : (binB > GG - 1 ? GG - 1 : binB);
        atomicAdd(&ghist[w][binA], 1);
        atomicAdd(&ghist[4 + w][binB], 1);
    }
    const unsigned long long below = (lane == 0) ? 0ull : (~0ull >> (64 - lane));
    unsigned long long mA = ~0ull, mB = ~0ull;
#pragma unroll
    for (int bit = 0; bit < 7; ++bit) {
        unsigned long long bA = __ballot((binA >> bit) & 1);
        unsigned long long bB = __ballot((binB >> bit) & 1);
        mA &= ((binA >> bit) & 1) ? bA : ~bA;
        mB &= ((binB >> bit) & 1) ? bB : ~bB;
    }
    const int rA = __popcll(mA & below);
    const int rB = __popcll(mB & below);
    __syncthreads();

    int bc = 0;
    if (t < GG) {
        int s = 0;
#pragma unroll
        for (int g = 0; g < 8; ++g) { gpart[g][t] = s; s += ghist[g][t]; }
        bc = s;
    }
    int xs = bc;
#pragma unroll
    for (int off = 1; off < 64; off <<= 1) {
        int v = __shfl_up(xs, off, 64);
        if (lane >= off) xs += v;
    }
    if (t == 63) wtot = xs;
    __syncthreads();
    if (t >= 64 && t < GG) xs += wtot;
    if (t < GG) spre[t + 1] = xs;
    if (t == 0) spre[0] = 0;
    __syncthreads();

    inv[spre[binA] + gpart[w][binA] + rA]     = t;
    inv[spre[binB] + gpart[4 + w][binB] + rB] = t + 256;
    if (j0loc == 0 && t < GG + 1) pref[b * (GG + 1) + t] = spre[t];
    __syncthreads();

    if (t < NPB) {
        int nl = inv[j0loc + t];
        sn[t]  = nl;
        spy[t] = pos[(size_t)(nbase + nl) * 2 + 0];
        spx[t] = pos[(size_t)(nbase + nl) * 2 + 1];
    }
    __syncthreads();

    // ---- (b) separable weights for NPB sorted nodes ----
    const int g = t >> 4, c = t & 15;
    const float sig = expf(log_sigma[0]);
    const float inv2s2 = 1.0f / (2.0f * sig * sig);
    const float py = spy[c], px = spx[c];

    float pey = 0.f, pex = 0.f;
#pragma unroll
    for (int r = 0; r < 6; ++r) {
        int yy = r * 16 + g;
        float dy = (float)yy - py;
        float dx = (float)yy - px;
        float ey = expf(-dy * dy * inv2s2);
        float ex = expf(-dx * dx * inv2s2);
        sE[yy][c] = ey; sX[yy][c] = ex;
        pey += ey; pex += ex;
    }
    sPy[g][c] = pey; sPx[g][c] = pex;
    __syncthreads();

    if (t < NPB) {
        float sy = 0.f, sx = 0.f;
#pragma unroll
        for (int gg = 0; gg < 16; ++gg) { sy += sPy[gg][t]; sx += sPx[gg][t]; }
        sG[t] = 1.0f / (sy * sx + 1e-8f);
    }
    __syncthreads();

    const float gf = sG[c];
    const int jcol = nbase + j0loc;
#pragma unroll
    for (int r = 0; r < 6; ++r) {
        int yy = r * 16 + g;
        wygT[(size_t)yy * Nn + jcol + c] = sE[yy][c] * gf;
        wxT [(size_t)yy * Nn + jcol + c] = sX[yy][c];
    }
    __syncthreads();   // before sT overwrites ubig

    // ---- (c) gather-transpose-split f -> bf16 hi/lo ----
#pragma unroll
    for (int jj = 0; jj < 2; ++jj) {
        int idx = t + 256 * jj;               // 0..511
        int nl  = idx >> 5;                   // 0..15
        int cc  = idx & 31;                   // float4 column
        float4 v = *(const float4*)(f + (size_t)(nbase + sn[nl]) * DD + cc * 4);
        sT[cc * 4 + 0][nl] = v.x;
        sT[cc * 4 + 1][nl] = v.y;
        sT[cc * 4 + 2][nl] = v.z;
        sT[cc * 4 + 3][nl] = v.w;
    }
    __syncthreads();

    const int d = t >> 1, h = t & 1;
    unsigned int ph[4], pl[4];
#pragma unroll
    for (int q = 0; q < 4; ++q) {
        float x0 = sT[d][h * 8 + 2 * q];
        float x1 = sT[d][h * 8 + 2 * q + 1];
        __hip_bfloat16 h0 = __float2bfloat16(x0);
        __hip_bfloat16 h1 = __float2bfloat16(x1);
        __hip_bfloat16 l0 = __float2bfloat16(x0 - __bfloat162float(h0));
        __hip_bfloat16 l1 = __float2bfloat16(x1 - __bfloat162float(h1));
        unsigned short uh0 = *(const unsigned short*)&h0;
        unsigned short uh1 = *(const unsigned short*)&h1;
        unsigned short ul0 = *(const unsigned short*)&l0;
        unsigned short ul1 = *(const unsigned short*)&l1;
        ph[q] = (unsigned int)uh0 | ((unsigned int)uh1 << 16);
        pl[q] = (unsigned int)ul0 | ((unsigned int)ul1 << 16);
    }
    *(int4*)(fTh + (size_t)d * Nn + jcol + h * 8) = make_int4((int)ph[0], (int)ph[1], (int)ph[2], (int)ph[3]);
    *(int4*)(fTl + (size_t)d * Nn + jcol + h * 8) = make_int4((int)pl[0], (int)pl[1], (int)pl[2], (int)pl[3]);
}

// ================= splat body (R8-validated, RCUT=18) =================
__device__ void splat_body(
    const unsigned short* __restrict__ fTh, const unsigned short* __restrict__ fTl,
    const float* __restrict__ wygT, const float* __restrict__ wxT,
    const int* __restrict__ pref,
    float* __restrict__ out, int Nn, int n_per)
{
    // XCD-chunked swizzle: XCD x owns batch x (y-major within batch).
    const int swz = ((int)blockIdx.x % 8) * GG + (int)blockIdx.x / 8;
    const int b = swz / GG;
    const int y = swz % GG;
    const int tid = (int)threadIdx.x;
    const int lane = tid & 63;
    const int wid  = tid >> 6;
    const int lr = lane & 15;
    const int kg = lane >> 4;

    __shared__ __align__(16) unsigned short sW[2][GG][APAD];  // 15 KiB dbuf

    f32x4 acc[2][6];
#pragma unroll
    for (int mi = 0; mi < 2; ++mi)
#pragma unroll
        for (int ni = 0; ni < 6; ++ni) acc[mi][ni] = (f32x4){0.f, 0.f, 0.f, 0.f};

    const int lob = y - RCUT < 0 ? 0 : y - RCUT;
    const int hib = y + RCUT > GG ? GG : y + RCUT;
    const int klo = pref[b * (GG + 1) + lob];
    const int khi = pref[b * (GG + 1) + hib];
    const int c0 = klo >> 5;
    const int c1 = (khi + 31) >> 5;

    const int nbase = b * n_per;
    const float* wyrow = wygT + (size_t)y * Nn;

    const int ar0 = wid * 32 + lr;
    const unsigned short* pH0 = fTh + (size_t)ar0 * Nn;
    const unsigned short* pH1 = fTh + (size_t)(ar0 + 16) * Nn;
    const unsigned short* pL0 = fTl + (size_t)ar0 * Nn;
    const unsigned short* pL1 = fTl + (size_t)(ar0 + 16) * Nn;

#define WGEN(CC, BUF)                                                              \
    {                                                                              \
        const int ncur_ = nbase + (CC) * KC;                                       \
        _Pragma("unroll")                                                          \
        for (int i_ = 0; i_ < 6; ++i_) {                                           \
            int p_  = tid + 256 * i_;                                              \
            int x_  = p_ >> 4;                                                     \
            int kp_ = p_ & 15;                                                     \
            float2 wy_ = *(const float2*)(wyrow + ncur_ + 2 * kp_);                \
            float2 wx_ = *(const float2*)(wxT + (size_t)x_ * Nn + ncur_ + 2 * kp_);\
            __hip_bfloat162 bb_ = __float22bfloat162_rn(                           \
                make_float2(wy_.x * wx_.x, wy_.y * wx_.y));                        \
            *(unsigned int*)&sW[BUF][x_][2 * kp_] = *(unsigned int*)&bb_;          \
        }                                                                          \
    }

    if (c0 < c1) WGEN(c0, 0);
    __syncthreads();

    int cur = 0;
    for (int c = c0; c < c1; ++c) {
        const int k0 = nbase + c * KC + kg * 8;
        short8v cah0 = *(const short8v*)(pH0 + k0);
        short8v cah1 = *(const short8v*)(pH1 + k0);
        short8v cal0 = *(const short8v*)(pL0 + k0);
        short8v cal1 = *(const short8v*)(pL1 + k0);

        if (c + 1 < c1) WGEN(c + 1, cur ^ 1);

#pragma unroll
        for (int ni = 0; ni < 6; ++ni) {
            short8v bv = *(const short8v*)&sW[cur][ni * 16 + lr][kg * 8];
            acc[0][ni] = __builtin_amdgcn_mfma_f32_16x16x32_bf16(cah0, bv, acc[0][ni], 0, 0, 0);
            acc[1][ni] = __builtin_amdgcn_mfma_f32_16x16x32_bf16(cah1, bv, acc[1][ni], 0, 0, 0);
            acc[0][ni] = __builtin_amdgcn_mfma_f32_16x16x32_bf16(cal0, bv, acc[0][ni], 0, 0, 0);
            acc[1][ni] = __builtin_amdgcn_mfma_f32_16x16x32_bf16(cal1, bv, acc[1][ni], 0, 0, 0);
        }
        __syncthreads();
        cur ^= 1;
    }

    // nt epilogue (R8-validated form)
#pragma unroll
    for (int mi = 0; mi < 2; ++mi)
#pragma unroll
        for (int ni = 0; ni < 6; ++ni) {
            const int d0 = wid * 32 + mi * 16 + kg * 4;
            const int x  = ni * 16 + lr;
            float* op = out + (((size_t)b * DD + d0) * GG + y) * GG + x;
#pragma unroll
            for (int r = 0; r < 4; ++r)
                __builtin_nontemporal_store(acc[mi][ni][r], op + (size_t)r * GG * GG);
        }
#undef WGEN
}

// ================= kernels =================
__global__ __launch_bounds__(256, 3) void fused(
    const float* __restrict__ pos, const float* __restrict__ lsig,
    const float* __restrict__ f,
    int* __restrict__ pref, float* __restrict__ wygT, float* __restrict__ wxT,
    unsigned short* __restrict__ fTh, unsigned short* __restrict__ fTl,
    float* __restrict__ out, int Nn, int n_per)
{
    if ((int)blockIdx.x < Nn / NPB)
        preprocess_body(pos, lsig, f, pref, wygT, wxT, fTh, fTl, Nn);
    __threadfence();
    cooperative_groups::this_grid().sync();
    splat_body(fTh, fTl, wygT, wxT, pref, out, Nn, n_per);
}

__global__ __launch_bounds__(256) void k_pre(
    const float* __restrict__ pos, const float* __restrict__ lsig,
    const float* __restrict__ f,
    int* __restrict__ pref, float* __restrict__ wygT, float* __restrict__ wxT,
    unsigned short* __restrict__ fTh, unsigned short* __restrict__ fTl, int Nn)
{
    preprocess_body(pos, lsig, f, pref, wygT, wxT, fTh, fTl, Nn);
}

__global__ __launch_bounds__(256, 3) void k_splat(
    const unsigned short* __restrict__ fTh, const unsigned short* __restrict__ fTl,
    const float* __restrict__ wygT, const float* __restrict__ wxT,
    const int* __restrict__ pref, float* __restrict__ out, int Nn, int n_per)
{
    splat_body(fTh, fTl, wygT, wxT, pref, out, Nn, n_per);
}

extern "C" void kernel_launch(void* const* d_in, const int* in_sizes, int n_in,
                              void* d_out, int out_size, void* d_ws, size_t ws_size,
                              hipStream_t stream) {
    const float* feat = (const float*)d_in[0];
    const float* pos  = (const float*)d_in[1];
    const float* lsig = (const float*)d_in[4];

    int N  = in_sizes[2];                              // 4096
    int B  = out_size / (DD * GG * GG);                // 8
    int n_per = N / B;                                 // 512 (== NPER)

    int* pref = (int*)d_ws;                            // B x 97
    float* wygT = (float*)(pref + B * (GG + 1));       // 96 x N f32
    float* wxT  = wygT + (size_t)GG * N;               // 96 x N f32
    unsigned short* fTh = (unsigned short*)(wxT + (size_t)GG * N);  // 128 x N bf16
    unsigned short* fTl = fTh + (size_t)DD * N;                     // 128 x N bf16
    float* outp = (float*)d_out;

    void* args[] = { (void*)&pos, (void*)&lsig, (void*)&feat,
                     (void*)&pref, (void*)&wygT, (void*)&wxT,
                     (void*)&fTh, (void*)&fTl, (void*)&outp,
                     (void*)&N, (void*)&n_per };

    hipError_t e = hipLaunchCooperativeKernel((const void*)fused,
                                              dim3(B * GG), dim3(256),
                                              args, 0, stream);
    if (e != hipSuccess) {
        // fallback: exact R8 two-kernel path
        k_pre<<<N / NPB, 256, 0, stream>>>(pos, lsig, feat, pref, wygT, wxT, fTh, fTl, N);
        k_splat<<<B * GG, 256, 0, stream>>>(fTh, fTl, wygT, wxT, pref, outp, N, n_per);
    }
}

// Round 12
// 31.401 us; speedup vs baseline: 5.8477x; 5.8477x over previous
//
#include <hip/hip_runtime.h>
#include <hip/hip_bf16.h>

#define GG    96     // grid size
#define DD    128    // feature dim
#define KC    32     // K-chunk = MFMA K
#define APAD  40     // padded LDS row stride in ushorts (80 B)
#define RCUT  18     // gaussian support radius in rows (exp(-18^2/32)=4e-5; validated R10)
#define NPER  512    // nodes per batch (N/B)
#define NPB   8      // nodes per preprocess block (512 blocks = 2/CU for TLP)

typedef __attribute__((ext_vector_type(8))) short short8v;  // 8 bf16 = 4 VGPRs
typedef __attribute__((ext_vector_type(4))) float f32x4;    // MFMA acc

// ---------------- Kernel 1: fused preprocess (8 nodes/block, 512 blocks) ----------------
__global__ __launch_bounds__(256) void preprocess(
    const float* __restrict__ pos, const float* __restrict__ log_sigma,
    const float* __restrict__ f,
    int* __restrict__ pref,
    float* __restrict__ wygT, float* __restrict__ wxT,
    unsigned short* __restrict__ fTh, unsigned short* __restrict__ fTl,
    int Nn)
{
    const int blk   = (int)blockIdx.x;
    const int bpb   = NPER / NPB;             // 64 blocks per batch
    const int b     = blk / bpb;
    const int j0loc = (blk % bpb) * NPB;
    const int nbase = b * NPER;
    const int t     = (int)threadIdx.x;
    const int w     = t >> 6, lane = t & 63;

    __shared__ int ghist[8][GG];
    __shared__ int gpart[8][GG];
    __shared__ int spre[GG + 1];
    __shared__ int inv[NPER];
    __shared__ int sn[NPB];
    __shared__ int wtot;
    __shared__ float spy[NPB], spx[NPB], sG[NPB];
    __shared__ float sPy[32][NPB], sPx[32][NPB];
    __shared__ __align__(16) float ubig[GG * NPB * 2];   // 6 KiB, phased reuse
    float (*sE)[NPB] = (float(*)[NPB])ubig;              // weights phase [96][8]
    float (*sX)[NPB] = (float(*)[NPB])(ubig + GG * NPB);
    float (*sT)[9]   = (float(*)[9])ubig;                // transpose phase [128][9]

    // ---- (a) in-LDS counting sort of the whole batch (redundant per block) ----
    for (int i = t; i < 8 * GG; i += 256) (&ghist[0][0])[i] = 0;
    __syncthreads();

    int binA, binB;
    {
        float pyA = pos[(size_t)(nbase + t) * 2];
        float pyB = pos[(size_t)(nbase + t + 256) * 2];
        binA = (int)floorf(pyA); binA = binA < 0 ? 0 : (binA > GG - 1 ? GG - 1 : binA);
        binB = (int)floorf(pyB); binB = binB < 0 ? 0 : (binB > GG - 1 ? GG - 1 : binB);
        atomicAdd(&ghist[w][binA], 1);
        atomicAdd(&ghist[4 + w][binB], 1);
    }
    const unsigned long long below = (lane == 0) ? 0ull : (~0ull >> (64 - lane));
    unsigned long long mA = ~0ull, mB = ~0ull;
#pragma unroll
    for (int bit = 0; bit < 7; ++bit) {
        unsigned long long bA = __ballot((binA >> bit) & 1);
        unsigned long long bB = __ballot((binB >> bit) & 1);
        mA &= ((binA >> bit) & 1) ? bA : ~bA;
        mB &= ((binB >> bit) & 1) ? bB : ~bB;
    }
    const int rA = __popcll(mA & below);
    const int rB = __popcll(mB & below);
    __syncthreads();

    int bc = 0;
    if (t < GG) {
        int s = 0;
#pragma unroll
        for (int g = 0; g < 8; ++g) { gpart[g][t] = s; s += ghist[g][t]; }
        bc = s;
    }
    // two-wave Kogge-Stone inclusive scan over the 96 bin counts
    int xs = bc;
#pragma unroll
    for (int off = 1; off < 64; off <<= 1) {
        int v = __shfl_up(xs, off, 64);
        if (lane >= off) xs += v;
    }
    if (t == 63) wtot = xs;
    __syncthreads();
    if (t >= 64 && t < GG) xs += wtot;
    if (t < GG) spre[t + 1] = xs;
    if (t == 0) spre[0] = 0;
    __syncthreads();

    inv[spre[binA] + gpart[w][binA] + rA]     = t;
    inv[spre[binB] + gpart[4 + w][binB] + rB] = t + 256;
    if (j0loc == 0 && t < GG + 1) pref[b * (GG + 1) + t] = spre[t];
    __syncthreads();

    if (t < NPB) {
        int nl = inv[j0loc + t];
        sn[t]  = nl;
        spy[t] = pos[(size_t)(nbase + nl) * 2 + 0];
        spx[t] = pos[(size_t)(nbase + nl) * 2 + 1];
    }
    __syncthreads();

    // ---- (b) separable weights for NPB sorted nodes ----
    const int g = t >> 3, c = t & 7;          // g: 32 y-groups, c: node
    const float sig = expf(log_sigma[0]);
    const float inv2s2 = 1.0f / (2.0f * sig * sig);
    const float py = spy[c], px = spx[c];

    float pey = 0.f, pex = 0.f;
#pragma unroll
    for (int r = 0; r < 3; ++r) {
        int yy = r * 32 + g;
        float dy = (float)yy - py;
        float dx = (float)yy - px;
        float ey = expf(-dy * dy * inv2s2);
        float ex = expf(-dx * dx * inv2s2);
        sE[yy][c] = ey; sX[yy][c] = ex;
        pey += ey; pex += ex;
    }
    sPy[g][c] = pey; sPx[g][c] = pex;
    __syncthreads();

    if (t < NPB) {
        float sy = 0.f, sx = 0.f;
#pragma unroll
        for (int gg = 0; gg < 32; ++gg) { sy += sPy[gg][t]; sx += sPx[gg][t]; }
        sG[t] = 1.0f / (sy * sx + 1e-8f);
    }
    __syncthreads();

    const float gf = sG[c];
    const int jcol = nbase + j0loc;
#pragma unroll
    for (int r = 0; r < 3; ++r) {
        int yy = r * 32 + g;
        wygT[(size_t)yy * Nn + jcol + c] = sE[yy][c] * gf;
        wxT [(size_t)yy * Nn + jcol + c] = sX[yy][c];
    }
    __syncthreads();   // before sT overwrites ubig

    // ---- (c) gather-transpose-split f -> bf16 hi/lo ----
    {
        int nl  = t >> 5;                     // 0..7
        int cc  = t & 31;                     // float4 column
        float4 v = *(const float4*)(f + (size_t)(nbase + sn[nl]) * DD + cc * 4);
        sT[cc * 4 + 0][nl] = v.x;
        sT[cc * 4 + 1][nl] = v.y;
        sT[cc * 4 + 2][nl] = v.z;
        sT[cc * 4 + 3][nl] = v.w;
    }
    __syncthreads();

    const int d = t >> 1, h = t & 1;          // d row, 4-node half
    unsigned int ph[2], pl[2];
#pragma unroll
    for (int q = 0; q < 2; ++q) {
        float x0 = sT[d][h * 4 + 2 * q];
        float x1 = sT[d][h * 4 + 2 * q + 1];
        __hip_bfloat16 h0 = __float2bfloat16(x0);
        __hip_bfloat16 h1 = __float2bfloat16(x1);
        __hip_bfloat16 l0 = __float2bfloat16(x0 - __bfloat162float(h0));
        __hip_bfloat16 l1 = __float2bfloat16(x1 - __bfloat162float(h1));
        unsigned short uh0 = *(const unsigned short*)&h0;
        unsigned short uh1 = *(const unsigned short*)&h1;
        unsigned short ul0 = *(const unsigned short*)&l0;
        unsigned short ul1 = *(const unsigned short*)&l1;
        ph[q] = (unsigned int)uh0 | ((unsigned int)uh1 << 16);
        pl[q] = (unsigned int)ul0 | ((unsigned int)ul1 << 16);
    }
    *(int2*)(fTh + (size_t)d * Nn + jcol + h * 4) = make_int2((int)ph[0], (int)ph[1]);
    *(int2*)(fTl + (size_t)d * Nn + jcol + h * 4) = make_int2((int)pl[0], (int)pl[1]);
}

// ---------------- Kernel 2: MFMA splat GEMM (R8-validated; RCUT=18) ----------------
__global__ __launch_bounds__(256, 3) void splat_mfma(
    const unsigned short* __restrict__ fTh, const unsigned short* __restrict__ fTl,
    const float* __restrict__ wygT, const float* __restrict__ wxT,
    const int* __restrict__ pref,
    float* __restrict__ out, int Nn, int n_per)
{
    // XCD-chunked swizzle: XCD x owns batch x (y-major within batch).
    const int swz = ((int)blockIdx.x % 8) * GG + (int)blockIdx.x / 8;
    const int b = swz / GG;
    const int y = swz % GG;
    const int tid = (int)threadIdx.x;
    const int lane = tid & 63;
    const int wid  = tid >> 6;
    const int lr = lane & 15;
    const int kg = lane >> 4;

    __shared__ __align__(16) unsigned short sW[2][GG][APAD];  // 15 KiB dbuf

    f32x4 acc[2][6];
#pragma unroll
    for (int mi = 0; mi < 2; ++mi)
#pragma unroll
        for (int ni = 0; ni < 6; ++ni) acc[mi][ni] = (f32x4){0.f, 0.f, 0.f, 0.f};

    const int lob = y - RCUT < 0 ? 0 : y - RCUT;
    const int hib = y + RCUT > GG ? GG : y + RCUT;
    const int klo = pref[b * (GG + 1) + lob];
    const int khi = pref[b * (GG + 1) + hib];
    const int c0 = klo >> 5;
    const int c1 = (khi + 31) >> 5;

    const int nbase = b * n_per;
    const float* wyrow = wygT + (size_t)y * Nn;

    const int ar0 = wid * 32 + lr;
    const unsigned short* pH0 = fTh + (size_t)ar0 * Nn;
    const unsigned short* pH1 = fTh + (size_t)(ar0 + 16) * Nn;
    const unsigned short* pL0 = fTl + (size_t)ar0 * Nn;
    const unsigned short* pL1 = fTl + (size_t)(ar0 + 16) * Nn;

#define WGEN(CC, BUF)                                                              \
    {                                                                              \
        const int ncur_ = nbase + (CC) * KC;                                       \
        _Pragma("unroll")                                                          \
        for (int i_ = 0; i_ < 6; ++i_) {                                           \
            int p_  = tid + 256 * i_;                                              \
            int x_  = p_ >> 4;                                                     \
            int kp_ = p_ & 15;                                                     \
            float2 wy_ = *(const float2*)(wyrow + ncur_ + 2 * kp_);                \
            float2 wx_ = *(const float2*)(wxT + (size_t)x_ * Nn + ncur_ + 2 * kp_);\
            __hip_bfloat162 bb_ = __float22bfloat162_rn(                           \
                make_float2(wy_.x * wx_.x, wy_.y * wx_.y));                        \
            *(unsigned int*)&sW[BUF][x_][2 * kp_] = *(unsigned int*)&bb_;          \
        }                                                                          \
    }

    if (c0 < c1) WGEN(c0, 0);
    __syncthreads();

    int cur = 0;
    for (int c = c0; c < c1; ++c) {
        const int k0 = nbase + c * KC + kg * 8;
        short8v cah0 = *(const short8v*)(pH0 + k0);
        short8v cah1 = *(const short8v*)(pH1 + k0);
        short8v cal0 = *(const short8v*)(pL0 + k0);
        short8v cal1 = *(const short8v*)(pL1 + k0);

        if (c + 1 < c1) WGEN(c + 1, cur ^ 1);

#pragma unroll
        for (int ni = 0; ni < 6; ++ni) {
            short8v bv = *(const short8v*)&sW[cur][ni * 16 + lr][kg * 8];
            acc[0][ni] = __builtin_amdgcn_mfma_f32_16x16x32_bf16(cah0, bv, acc[0][ni], 0, 0, 0);
            acc[1][ni] = __builtin_amdgcn_mfma_f32_16x16x32_bf16(cah1, bv, acc[1][ni], 0, 0, 0);
            acc[0][ni] = __builtin_amdgcn_mfma_f32_16x16x32_bf16(cal0, bv, acc[0][ni], 0, 0, 0);
            acc[1][ni] = __builtin_amdgcn_mfma_f32_16x16x32_bf16(cal1, bv, acc[1][ni], 0, 0, 0);
        }
        __syncthreads();
        cur ^= 1;
    }

    // nt epilogue (R8-validated form)
#pragma unroll
    for (int mi = 0; mi < 2; ++mi)
#pragma unroll
        for (int ni = 0; ni < 6; ++ni) {
            const int d0 = wid * 32 + mi * 16 + kg * 4;
            const int x  = ni * 16 + lr;
            float* op = out + (((size_t)b * DD + d0) * GG + y) * GG + x;
#pragma unroll
            for (int r = 0; r < 4; ++r)
                __builtin_nontemporal_store(acc[mi][ni][r], op + (size_t)r * GG * GG);
        }
#undef WGEN
}

extern "C" void kernel_launch(void* const* d_in, const int* in_sizes, int n_in,
                              void* d_out, int out_size, void* d_ws, size_t ws_size,
                              hipStream_t stream) {
    const float* feat = (const float*)d_in[0];
    const float* pos  = (const float*)d_in[1];
    const float* lsig = (const float*)d_in[4];

    const int N  = in_sizes[2];                        // 4096
    const int B  = out_size / (DD * GG * GG);          // 8
    const int n_per = N / B;                           // 512 (== NPER)

    int* pref = (int*)d_ws;                            // B x 97
    float* wygT = (float*)(pref + B * (GG + 1));       // 96 x N f32
    float* wxT  = wygT + (size_t)GG * N;               // 96 x N f32
    unsigned short* fTh = (unsigned short*)(wxT + (size_t)GG * N);  // 128 x N bf16
    unsigned short* fTl = fTh + (size_t)DD * N;                     // 128 x N bf16

    preprocess<<<N / NPB, 256, 0, stream>>>(pos, lsig, feat, pref, wygT, wxT, fTh, fTl, N);

    splat_mfma<<<B * GG, 256, 0, stream>>>(fTh, fTl, wygT, wxT, pref, (float*)d_out, N, n_per);
}